// Round 1
// baseline (705.739 us; speedup 1.0000x reference)
//
#include <hip/hip_runtime.h>
#include <stdint.h>
#include <stddef.h>

// ---------- types ----------
typedef __attribute__((ext_vector_type(4))) float f32x4;
typedef __attribute__((ext_vector_type(4))) int   i32x4;
typedef __attribute__((ext_vector_type(8))) short s16x8;
typedef __attribute__((ext_vector_type(4))) short s16x4;
typedef __attribute__((ext_vector_type(8))) __bf16 bf16x8;

#define AS3 __attribute__((address_space(3)))
#define AS1 __attribute__((address_space(1)))

__device__ inline void gload16(const void* g, void* l) {
  // async global->LDS, 16B per lane; LDS dest = wave-uniform base + lane*16
  __builtin_amdgcn_global_load_lds((AS1 const void*)g, (AS3 void*)l, 16, 0, 0);
}

__device__ inline f32x4 mfma16(s16x8 a, s16x8 b, f32x4 c) {
  return __builtin_amdgcn_mfma_f32_16x16x32_bf16(
      __builtin_bit_cast(bf16x8, a), __builtin_bit_cast(bf16x8, b), c, 0, 0, 0);
}

__device__ inline short f2bf(float f) {  // RNE float->bf16 bits
  unsigned u = __builtin_bit_cast(unsigned, f);
  u += 0x7FFFu + ((u >> 16) & 1u);
  return (short)(u >> 16);
}
__device__ inline float bf2f(short x) {
  unsigned u = ((unsigned)(unsigned short)x) << 16;
  return __builtin_bit_cast(float, u);
}

// ---------- fused cast f32 -> bf16 of x, W_in, W_out (one launch) ----------
// ranges in f32x4 units: x 1048576 | W_in 786432 | W_out 262144  (total 2097152)
__global__ void cast_all(const float* __restrict__ x, const float* __restrict__ wi,
                         const float* __restrict__ wo, short* __restrict__ xb,
                         short* __restrict__ wib, short* __restrict__ wob) {
  int i = blockIdx.x * 256 + threadIdx.x;
  const float* src;
  short* dst;
  int off;
  if (i < 1048576)      { src = x;  dst = xb;  off = i; }
  else if (i < 1835008) { src = wi; dst = wib; off = i - 1048576; }
  else                  { src = wo; dst = wob; off = i - 1835008; }
  f32x4 v = *(const f32x4*)(src + (size_t)off * 4);
  s16x4 o;
#pragma unroll
  for (int r = 0; r < 4; ++r) o[r] = f2bf(v[r]);
  *(s16x4*)(dst + (size_t)off * 4) = o;
}

// ---------- GEMM: C[M][N] = A[M][K](bf16) * B[N][K](bf16)^T + bias[N] ----------
// FR=4: 128x128 tile (4 waves as 2x2 of 64x64). FR=2: 64x64 tile (2x2 of 32x32).
template <int OBF, int FR>
__global__ __launch_bounds__(256, 2) void gemm_bt(
    const short* __restrict__ A, const short* __restrict__ B,
    const float* __restrict__ bias, void* __restrict__ Cv,
    int M, int N, int K) {
  const int TILE = FR * 32;
  const int tid = threadIdx.x, w = tid >> 6, lane = tid & 63;
  const int quad = lane >> 4, l15 = lane & 15;
  const int wm = w >> 1, wn = w & 1;
  const int m0 = blockIdx.y * TILE, n0 = blockIdx.x * TILE;
  __shared__ short As[TILE * 32], Bs[TILE * 32];
  f32x4 acc[FR][FR];
#pragma unroll
  for (int i = 0; i < FR; ++i)
#pragma unroll
    for (int j = 0; j < FR; ++j) acc[i][j] = (f32x4){0.f, 0.f, 0.f, 0.f};
  const int rs = lane >> 2, cs = (lane & 3) * 8;
  const int nkt = K >> 5;
  for (int kt = 0; kt < nkt; ++kt) {
    const int k0 = kt * 32;
#pragma unroll
    for (int j = 0; j < FR / 2; ++j) {
      gload16(A + (size_t)(m0 + w * (FR * 8) + j * 16 + rs) * K + k0 + cs,
              &As[w * (FR * 256) + j * 512]);
      gload16(B + (size_t)(n0 + w * (FR * 8) + j * 16 + rs) * K + k0 + cs,
              &Bs[w * (FR * 256) + j * 512]);
    }
    __syncthreads();
    s16x8 af[FR], bfr[FR];
#pragma unroll
    for (int i = 0; i < FR; ++i) {
      af[i]  = *(const s16x8*)&As[(wm * (FR * 16) + i * 16 + l15) * 32 + quad * 8];
      bfr[i] = *(const s16x8*)&Bs[(wn * (FR * 16) + i * 16 + l15) * 32 + quad * 8];
    }
#pragma unroll
    for (int ms = 0; ms < FR; ++ms)
#pragma unroll
      for (int ns = 0; ns < FR; ++ns)
        acc[ms][ns] = mfma16(af[ms], bfr[ns], acc[ms][ns]);
    __syncthreads();
  }
#pragma unroll
  for (int ms = 0; ms < FR; ++ms) {
    const int row0 = m0 + wm * (FR * 16) + ms * 16 + quad * 4;
#pragma unroll
    for (int ns = 0; ns < FR; ++ns) {
      const int col = n0 + wn * (FR * 16) + ns * 16 + l15;
      const float bv = bias[col];
#pragma unroll
      for (int r = 0; r < 4; ++r) {
        float v = acc[ms][ns][r] + bv;
        if (OBF) ((short*)Cv)[(size_t)(row0 + r) * N + col] = f2bf(v);
        else     ((float*)Cv)[(size_t)(row0 + r) * N + col] = v;
      }
    }
  }
}

// ---------- fused repack: qkv -> qh [bh][s][d] (x1/8), kh [bh][s][d], vT [bh][d][s]
// grid (64 bh, 16 s-tiles of 64), 256 threads
__global__ void repack_all(const short* __restrict__ qkv, short* __restrict__ qh,
                           short* __restrict__ kh, short* __restrict__ vT) {
  __shared__ short t[64][80];  // v tile [s][d], pad 80 shorts (160B rows, 16B-mult)
  const int bh = blockIdx.x, st_ = blockIdx.y;
  const int b_ = bh >> 4, h_ = bh & 15;
  const int tid = threadIdx.x;
  // q/k: 64 s x 2 types x 8 chunks = 1024 chunks of 8 shorts
#pragma unroll
  for (int part = 0; part < 4; ++part) {
    int lin = part * 256 + tid;
    int dg = lin & 7, ty = (lin >> 3) & 1, s_l = lin >> 4;
    int s = st_ * 64 + s_l;
    s16x8 v = *(const s16x8*)(qkv + (size_t)(s * 4 + b_) * 3072 + h_ * 192 + ty * 64 + dg * 8);
    if (ty == 0) {
#pragma unroll
      for (int i = 0; i < 8; ++i) v[i] = f2bf(bf2f(v[i]) * 0.125f);
      *(s16x8*)&qh[((size_t)bh << 16) + (size_t)s * 64 + dg * 8] = v;
    } else {
      *(s16x8*)&kh[((size_t)bh << 16) + (size_t)s * 64 + dg * 8] = v;
    }
  }
  // v load: 64 s x 8 chunks = 512 chunks
#pragma unroll
  for (int part = 0; part < 2; ++part) {
    int lin = part * 256 + tid;
    int ch = lin & 7, s_l = lin >> 3;
    int s = st_ * 64 + s_l;
    *(s16x8*)&t[s_l][ch * 8] =
        *(const s16x8*)(qkv + (size_t)(s * 4 + b_) * 3072 + h_ * 192 + 128 + ch * 8);
  }
  __syncthreads();
  // v transpose out: 64 d x 8 s-chunks = 512 chunks
#pragma unroll
  for (int part = 0; part < 2; ++part) {
    int lin = part * 256 + tid;
    int sc = lin & 7, d_l = lin >> 3;
    s16x8 vv;
#pragma unroll
    for (int j = 0; j < 8; ++j) vv[j] = t[sc * 8 + j][d_l];
    *(s16x8*)&vT[((size_t)bh << 16) + (size_t)d_l * 1024 + st_ * 64 + sc * 8] = vv;
  }
}

// ---------- fused flash attention with softmax_1, bias add/mul, key mask ----------
// grid (64 bh, 16 q-tiles of 64), 256 thr = 4 waves, each wave 16 q; k-tiles of 32.
// BARRIER-FREE: K/V tiles are read as MFMA fragments directly from global (L2/L3
// resident: 16 MB total, reused 64x). No LDS staging, no __syncthreads in the
// K-loop -> no vmcnt(0) drains, so the bias/abm register prefetch stays in flight.
__global__ __launch_bounds__(256, 4) void attn_fused(
    const short* __restrict__ qh, const short* __restrict__ kh,
    const short* __restrict__ vT, const float* __restrict__ bias,
    const float* __restrict__ abm, const int* __restrict__ kpm,
    short* __restrict__ attnbf) {
  const int tid = threadIdx.x;
  const int w = tid >> 6, lane = tid & 63, quad = lane >> 4, l15 = lane & 15;
  const int bh = blockIdx.x, qb = blockIdx.y;
  const int b_ = bh >> 4, h_ = bh & 15;
  const short* khd = kh + ((size_t)bh << 16);
  const short* vTd = vT + ((size_t)bh << 16);
  const int qw = qb * 64 + w * 16;
  // per-lane row bases for the streamed bias/abm (q row = qw + l15)
  const float* biasd = bias + ((size_t)bh << 20) + (size_t)(qw + l15) * 1024;
  const float* abmd  = abm  + ((size_t)bh << 20) + (size_t)(qw + l15) * 1024;
  const int*   kpmd  = kpm + (b_ << 10);

  __shared__ short wl[4][16 * 40];     // per-wave P tile [q][k], pad 40 (2-way, free)
  __shared__ float alds[4][16];        // per-wave per-q broadcast

  s16x8 qf[2];  // B-operand frags of Q^T (16 q rows), d-halves
#pragma unroll
  for (int t = 0; t < 2; ++t)
    qf[t] = *(const s16x8*)&qh[((size_t)bh << 16) + (size_t)(qw + l15) * 64 + t * 32 + quad * 8];

  f32x4 o[4];
#pragma unroll
  for (int ds = 0; ds < 4; ++ds) o[ds] = (f32x4){0.f, 0.f, 0.f, 0.f};
  float mrun = -1e30f, lrun = 0.f;

  struct Pack { f32x4 bs[2]; f32x4 ab[2]; i32x4 kp[2]; };
  Pack P0, P1;

  auto loadP = [&](int kt, Pack& P) {
    const int kb = kt * 32;
#pragma unroll
    for (int ms = 0; ms < 2; ++ms) {
      P.bs[ms] = *(const f32x4*)&biasd[kb + ms * 16 + quad * 4];
      P.ab[ms] = *(const f32x4*)&abmd [kb + ms * 16 + quad * 4];
      P.kp[ms] = *(const i32x4*)&kpmd[kb + ms * 16 + quad * 4];
    }
  };

  auto compute = [&](int kt, Pack& P) {
    const int kb = kt * 32;
    const f32x4 z4 = {0.f, 0.f, 0.f, 0.f};
    // V frags direct from global (L2) — issued early, consumed after softmax
    s16x8 vf[4];
#pragma unroll
    for (int ds = 0; ds < 4; ++ds)
      vf[ds] = *(const s16x8*)&vTd[(size_t)(ds * 16 + l15) * 1024 + kb + quad * 8];
    // K frags direct from global (L2); same index math the LDS tile used
    f32x4 st[2];  // S^T frags: rows=k (ms*16+quad*4+r), cols=q (l15)
#pragma unroll
    for (int ms = 0; ms < 2; ++ms) {
      s16x8 a0 = *(const s16x8*)&khd[(size_t)(kb + ms * 16 + l15) * 64 + quad * 8];
      s16x8 a1 = *(const s16x8*)&khd[(size_t)(kb + ms * 16 + l15) * 64 + 32 + quad * 8];
      st[ms] = mfma16(a1, qf[1], mfma16(a0, qf[0], z4));
    }
    float mloc = -1e30f;
#pragma unroll
    for (int ms = 0; ms < 2; ++ms)
#pragma unroll
      for (int r = 0; r < 4; ++r) {
        float sc = st[ms][r] + P.bs[ms][r];
        sc = (P.kp[ms][r] != 0) ? -1e30f : sc;
        st[ms][r] = sc;
        mloc = fmaxf(mloc, sc);
      }
    mloc = fmaxf(mloc, __shfl_xor(mloc, 16));
    mloc = fmaxf(mloc, __shfl_xor(mloc, 32));
    float mn = fmaxf(mrun, mloc);
    float al = __expf(mrun - mn);
    mrun = mn;
    float lloc = 0.f;
#pragma unroll
    for (int ms = 0; ms < 2; ++ms)
#pragma unroll
      for (int r = 0; r < 4; ++r) {
        // force e=0 on masked keys (guards all-masked-tile m=-1e30 corner too)
        float e = (P.kp[ms][r] != 0) ? 0.f : __expf(st[ms][r] - mrun);
        st[ms][r] = e;
        lloc += e;
      }
    lloc += __shfl_xor(lloc, 16);
    lloc += __shfl_xor(lloc, 32);
    lrun = lrun * al + lloc;
    alds[w][l15] = al;  // all quads write identical value
#pragma unroll
    for (int ms = 0; ms < 2; ++ms) {
      s16x4 pk;
#pragma unroll
      for (int r = 0; r < 4; ++r) pk[r] = f2bf(st[ms][r] * P.ab[ms][r]);
      *(s16x4*)&wl[w][l15 * 40 + ms * 16 + quad * 4] = pk;
    }
    f32x4 av = *(const f32x4*)&alds[w][quad * 4];
    s16x8 pf = *(const s16x8*)&wl[w][l15 * 40 + quad * 8];
#pragma unroll
    for (int ds = 0; ds < 4; ++ds) o[ds] *= av;
#pragma unroll
    for (int ds = 0; ds < 4; ++ds)
      o[ds] = mfma16(pf, vf[ds], o[ds]);
  };

  loadP(0, P0);
  loadP(1, P1);
  for (int kt = 0; kt < 32; kt += 2) {
    compute(kt, P0);
    if (kt + 2 < 32) loadP(kt + 2, P0);
    compute(kt + 1, P1);
    if (kt + 3 < 32) loadP(kt + 3, P1);
  }

  float rd = 1.f / (__expf(-mrun) + lrun);  // softmax_1 denominator
  alds[w][l15] = rd;
  f32x4 rdv = *(const f32x4*)&alds[w][quad * 4];
#pragma unroll
  for (int ds = 0; ds < 4; ++ds) {
    f32x4 ov = o[ds] * rdv;
#pragma unroll
    for (int r = 0; r < 4; ++r) {
      int s = qw + quad * 4 + r;
      attnbf[(size_t)(s * 4 + b_) * 1024 + h_ * 64 + ds * 16 + l15] = f2bf(ov[r]);
    }
  }
}

// ---------- launcher ----------
extern "C" void kernel_launch(void* const* d_in, const int* in_sizes, int n_in,
                              void* d_out, int out_size, void* d_ws, size_t ws_size,
                              hipStream_t stream) {
  const float* x     = (const float*)d_in[0];
  const float* bias  = (const float*)d_in[1];
  const float* abm   = (const float*)d_in[2];
  const int*   kpm   = (const int*)  d_in[3];
  const float* W_in  = (const float*)d_in[4];
  const float* b_in  = (const float*)d_in[5];
  const float* W_out = (const float*)d_in[6];
  const float* b_out = (const float*)d_in[7];
  float* out = (float*)d_out;

  char* ws = (char*)d_ws;
  short* xbf    = (short*)(ws);                              // 8 MB
  short* wibf   = (short*)(ws + (8u << 20));                 // 6 MB
  short* wobf   = (short*)(ws + (14u << 20) + (512u << 10)); // 2 MB
  short* qkvbf  = (short*)(ws + (16u << 20) + (768u << 10)); // 24 MB
  short* qh     = (short*)(ws + (40u << 20) + (768u << 10)); // 8 MB
  short* kh     = (short*)(ws + (48u << 20) + (768u << 10)); // 8 MB
  short* vTh    = (short*)(ws + (56u << 20) + (768u << 10)); // 8 MB
  short* attnbf = (short*)(ws + (64u << 20) + (768u << 10)); // 8 MB

  cast_all<<<8192, 256, 0, stream>>>(x, W_in, W_out, xbf, wibf, wobf);

  // qkv = x @ W_in^T + b_in  -> bf16
  gemm_bt<1, 4><<<dim3(24, 32), 256, 0, stream>>>(xbf, wibf, b_in, (void*)qkvbf,
                                                  4096, 3072, 1024);

  repack_all<<<dim3(64, 16), 256, 0, stream>>>(qkvbf, qh, kh, vTh);

  attn_fused<<<dim3(64, 16), 256, 0, stream>>>(qh, kh, vTh, bias, abm, kpm, attnbf);

  // out = attn @ W_out^T + b_out -> f32 (64x64 tiles: 1024 blocks = 4/CU)
  gemm_bt<0, 2><<<dim3(16, 64), 256, 0, stream>>>(attnbf, wobf, b_out, (void*)out,
                                                  4096, 1024, 1024);
}

// Round 2
// 657.334 us; speedup vs baseline: 1.0736x; 1.0736x over previous
//
#include <hip/hip_runtime.h>
#include <stdint.h>
#include <stddef.h>

// ---------- types ----------
typedef __attribute__((ext_vector_type(4))) float f32x4;
typedef __attribute__((ext_vector_type(4))) int   i32x4;
typedef __attribute__((ext_vector_type(8))) short s16x8;
typedef __attribute__((ext_vector_type(4))) short s16x4;
typedef __attribute__((ext_vector_type(8))) __bf16 bf16x8;

#define AS3 __attribute__((address_space(3)))
#define AS1 __attribute__((address_space(1)))

__device__ inline void gload16(const void* g, void* l) {
  // async global->LDS, 16B per lane; LDS dest = wave-uniform base + lane*16
  __builtin_amdgcn_global_load_lds((AS1 const void*)g, (AS3 void*)l, 16, 0, 0);
}

__device__ inline f32x4 mfma16(s16x8 a, s16x8 b, f32x4 c) {
  return __builtin_amdgcn_mfma_f32_16x16x32_bf16(
      __builtin_bit_cast(bf16x8, a), __builtin_bit_cast(bf16x8, b), c, 0, 0, 0);
}

__device__ inline short f2bf(float f) {  // RNE float->bf16 bits
  unsigned u = __builtin_bit_cast(unsigned, f);
  u += 0x7FFFu + ((u >> 16) & 1u);
  return (short)(u >> 16);
}
__device__ inline float bf2f(short x) {
  unsigned u = ((unsigned)(unsigned short)x) << 16;
  return __builtin_bit_cast(float, u);
}

// ---------- fused cast f32 -> bf16 of x, W_in, W_out (one launch) ----------
// ranges in f32x4 units: x 1048576 | W_in 786432 | W_out 262144  (total 2097152)
__global__ void cast_all(const float* __restrict__ x, const float* __restrict__ wi,
                         const float* __restrict__ wo, short* __restrict__ xb,
                         short* __restrict__ wib, short* __restrict__ wob) {
  int i = blockIdx.x * 256 + threadIdx.x;
  const float* src;
  short* dst;
  int off;
  if (i < 1048576)      { src = x;  dst = xb;  off = i; }
  else if (i < 1835008) { src = wi; dst = wib; off = i - 1048576; }
  else                  { src = wo; dst = wob; off = i - 1835008; }
  f32x4 v = *(const f32x4*)(src + (size_t)off * 4);
  s16x4 o;
#pragma unroll
  for (int r = 0; r < 4; ++r) o[r] = f2bf(v[r]);
  *(s16x4*)(dst + (size_t)off * 4) = o;
}

// ---------- GEMM: C[M][N] = A[M][K](bf16) * B[N][K](bf16)^T + bias[N] ----------
// FR=4: 128x128 tile (4 waves as 2x2 of 64x64). FR=2: 64x64 tile (2x2 of 32x32).
template <int OBF, int FR>
__global__ __launch_bounds__(256, 2) void gemm_bt(
    const short* __restrict__ A, const short* __restrict__ B,
    const float* __restrict__ bias, void* __restrict__ Cv,
    int M, int N, int K) {
  const int TILE = FR * 32;
  const int tid = threadIdx.x, w = tid >> 6, lane = tid & 63;
  const int quad = lane >> 4, l15 = lane & 15;
  const int wm = w >> 1, wn = w & 1;
  const int m0 = blockIdx.y * TILE, n0 = blockIdx.x * TILE;
  __shared__ short As[TILE * 32], Bs[TILE * 32];
  f32x4 acc[FR][FR];
#pragma unroll
  for (int i = 0; i < FR; ++i)
#pragma unroll
    for (int j = 0; j < FR; ++j) acc[i][j] = (f32x4){0.f, 0.f, 0.f, 0.f};
  const int rs = lane >> 2, cs = (lane & 3) * 8;
  const int nkt = K >> 5;
  for (int kt = 0; kt < nkt; ++kt) {
    const int k0 = kt * 32;
#pragma unroll
    for (int j = 0; j < FR / 2; ++j) {
      gload16(A + (size_t)(m0 + w * (FR * 8) + j * 16 + rs) * K + k0 + cs,
              &As[w * (FR * 256) + j * 512]);
      gload16(B + (size_t)(n0 + w * (FR * 8) + j * 16 + rs) * K + k0 + cs,
              &Bs[w * (FR * 256) + j * 512]);
    }
    __syncthreads();
    s16x8 af[FR], bfr[FR];
#pragma unroll
    for (int i = 0; i < FR; ++i) {
      af[i]  = *(const s16x8*)&As[(wm * (FR * 16) + i * 16 + l15) * 32 + quad * 8];
      bfr[i] = *(const s16x8*)&Bs[(wn * (FR * 16) + i * 16 + l15) * 32 + quad * 8];
    }
#pragma unroll
    for (int ms = 0; ms < FR; ++ms)
#pragma unroll
      for (int ns = 0; ns < FR; ++ns)
        acc[ms][ns] = mfma16(af[ms], bfr[ns], acc[ms][ns]);
    __syncthreads();
  }
#pragma unroll
  for (int ms = 0; ms < FR; ++ms) {
    const int row0 = m0 + wm * (FR * 16) + ms * 16 + quad * 4;
#pragma unroll
    for (int ns = 0; ns < FR; ++ns) {
      const int col = n0 + wn * (FR * 16) + ns * 16 + l15;
      const float bv = bias[col];
#pragma unroll
      for (int r = 0; r < 4; ++r) {
        float v = acc[ms][ns][r] + bv;
        if (OBF) ((short*)Cv)[(size_t)(row0 + r) * N + col] = f2bf(v);
        else     ((float*)Cv)[(size_t)(row0 + r) * N + col] = v;
      }
    }
  }
}

// ---------- fused repack: qkv -> qh [bh][s][d] (x1/8), kh [bh][s][d], vT [bh][d][s]
// grid (64 bh, 16 s-tiles of 64), 256 threads
__global__ void repack_all(const short* __restrict__ qkv, short* __restrict__ qh,
                           short* __restrict__ kh, short* __restrict__ vT) {
  __shared__ short t[64][80];  // v tile [s][d], pad 80 shorts (160B rows, 16B-mult)
  const int bh = blockIdx.x, st_ = blockIdx.y;
  const int b_ = bh >> 4, h_ = bh & 15;
  const int tid = threadIdx.x;
  // q/k: 64 s x 2 types x 8 chunks = 1024 chunks of 8 shorts
#pragma unroll
  for (int part = 0; part < 4; ++part) {
    int lin = part * 256 + tid;
    int dg = lin & 7, ty = (lin >> 3) & 1, s_l = lin >> 4;
    int s = st_ * 64 + s_l;
    s16x8 v = *(const s16x8*)(qkv + (size_t)(s * 4 + b_) * 3072 + h_ * 192 + ty * 64 + dg * 8);
    if (ty == 0) {
#pragma unroll
      for (int i = 0; i < 8; ++i) v[i] = f2bf(bf2f(v[i]) * 0.125f);
      *(s16x8*)&qh[((size_t)bh << 16) + (size_t)s * 64 + dg * 8] = v;
    } else {
      *(s16x8*)&kh[((size_t)bh << 16) + (size_t)s * 64 + dg * 8] = v;
    }
  }
  // v load: 64 s x 8 chunks = 512 chunks
#pragma unroll
  for (int part = 0; part < 2; ++part) {
    int lin = part * 256 + tid;
    int ch = lin & 7, s_l = lin >> 3;
    int s = st_ * 64 + s_l;
    *(s16x8*)&t[s_l][ch * 8] =
        *(const s16x8*)(qkv + (size_t)(s * 4 + b_) * 3072 + h_ * 192 + 128 + ch * 8);
  }
  __syncthreads();
  // v transpose out: 64 d x 8 s-chunks = 512 chunks
#pragma unroll
  for (int part = 0; part < 2; ++part) {
    int lin = part * 256 + tid;
    int sc = lin & 7, d_l = lin >> 3;
    s16x8 vv;
#pragma unroll
    for (int j = 0; j < 8; ++j) vv[j] = t[sc * 8 + j][d_l];
    *(s16x8*)&vT[((size_t)bh << 16) + (size_t)d_l * 1024 + st_ * 64 + sc * 8] = vv;
  }
}

// ---------- fused flash attention with softmax_1, bias add/mul, key mask ----------
// grid (64 bh, 16 q-tiles of 64), 256 thr = 4 waves, each wave 16 q; k-tiles of 32.
// Pipeline: 4-deep K/V LDS buffers + 3 rotating bias/abm register packs, counted
// s_waitcnt vmcnt(12) + raw s_barrier (T4) so 2 iterations of loads stay in
// flight across barriers (no vmcnt(0) drain). K/V LDS XOR-swizzled via
// pre-swizzled global source (rule #21): kbuf 16-way -> 2-way, vbuf 8-way -> 4-way.
__global__ __launch_bounds__(256, 3) void attn_fused(
    const short* __restrict__ qh, const short* __restrict__ kh,
    const short* __restrict__ vT, const float* __restrict__ bias,
    const float* __restrict__ abm, const int* __restrict__ kpm,
    short* __restrict__ attnbf) {
  const int tid = threadIdx.x;
  const int w = tid >> 6, lane = tid & 63, quad = lane >> 4, l15 = lane & 15;
  const int bh = blockIdx.x, qb = blockIdx.y;
  const int b_ = bh >> 4, h_ = bh & 15;
  const short* qhd = qh + ((size_t)bh << 16);
  const short* khd = kh + ((size_t)bh << 16);
  const short* vTd = vT + ((size_t)bh << 16);
  const int qw = qb * 64 + w * 16;
  const float* biasd = bias + ((size_t)bh << 20) + (size_t)(qw + l15) * 1024;
  const float* abmd  = abm  + ((size_t)bh << 20) + (size_t)(qw + l15) * 1024;
  const int*   kpmd  = kpm + (b_ << 10);

  __shared__ short kbuf[4][32 * 64];   // [k][d], rows 128B, src-swizzled
  __shared__ short vbuf[4][64 * 32];   // [d][k], rows 64B, src-swizzled
  __shared__ short wl[4][16 * 40];     // per-wave P tile [q][k], pad 40
  __shared__ float alds[4][16];        // per-wave per-q broadcast
  __shared__ int   kpl[1024];          // key padding mask, staged once

  s16x8 qf[2];  // B-operand frags of Q^T (16 q rows), d-halves
#pragma unroll
  for (int t = 0; t < 2; ++t)
    qf[t] = *(const s16x8*)&qhd[(size_t)(qw + l15) * 64 + t * 32 + quad * 8];

  f32x4 o[4];
#pragma unroll
  for (int ds = 0; ds < 4; ++ds) o[ds] = (f32x4){0.f, 0.f, 0.f, 0.f};
  float mrun = -1e30f, lrun = 0.f;

  struct Pack { f32x4 bs[2]; f32x4 ab[2]; };
  Pack P[3];

  // staging with source-side XOR swizzle (LDS dest stays linear for gload16)
  const int l7 = lane & 7, lr3 = lane >> 3;         // K: row sub-idx, slot
  const int l3 = lane & 3, lr2 = (lane >> 2) & 3;   // V
  auto stage = [&](int kt, int pb) {
    // K: lane -> row rK = w*8 + (lane>>3), slot (lane&7); src slot ^= rK&7
    gload16(khd + (size_t)kt * 2048 + (size_t)(w * 8 + lr3) * 64 + (size_t)(l7 ^ lr3) * 8,
            &kbuf[pb][w * 512]);
    // V: lane -> row rV = w*16 + (lane>>2), slot (lane&3); src slot ^= rV&3
    gload16(vTd + (size_t)(w * 16 + (lane >> 2)) * 1024 + kt * 32 + (size_t)(l3 ^ lr2) * 8,
            &vbuf[pb][w * 512]);
  };
  auto loadP = [&](int kt, Pack& Pp) {
    const int kb = kt * 32;
#pragma unroll
    for (int ms = 0; ms < 2; ++ms) {
      Pp.bs[ms] = *(const f32x4*)&biasd[kb + ms * 16 + quad * 4];
      Pp.ab[ms] = *(const f32x4*)&abmd [kb + ms * 16 + quad * 4];
    }
  };

  auto compute = [&](int kt, int pb, Pack& Pp) {
    const int kb = kt * 32;
    const f32x4 z4 = {0.f, 0.f, 0.f, 0.f};
    i32x4 kp[2];
#pragma unroll
    for (int ms = 0; ms < 2; ++ms)
      kp[ms] = *(const i32x4*)&kpl[kb + ms * 16 + quad * 4];  // broadcast, free
    f32x4 st[2];  // S^T frags: rows=k (ms*16+quad*4+r), cols=q (l15)
#pragma unroll
    for (int ms = 0; ms < 2; ++ms) {
      const int rK = ms * 16 + l15;
      const int sw = rK & 7;
      s16x8 a0 = *(const s16x8*)&kbuf[pb][rK * 64 + (quad ^ sw) * 8];
      s16x8 a1 = *(const s16x8*)&kbuf[pb][rK * 64 + ((quad + 4) ^ sw) * 8];
      st[ms] = mfma16(a1, qf[1], mfma16(a0, qf[0], z4));
    }
    float mloc = -1e30f;
#pragma unroll
    for (int ms = 0; ms < 2; ++ms)
#pragma unroll
      for (int r = 0; r < 4; ++r) {
        float sc = st[ms][r] + Pp.bs[ms][r];
        sc = (kp[ms][r] != 0) ? -1e30f : sc;
        st[ms][r] = sc;
        mloc = fmaxf(mloc, sc);
      }
    mloc = fmaxf(mloc, __shfl_xor(mloc, 16));
    mloc = fmaxf(mloc, __shfl_xor(mloc, 32));
    float mn = fmaxf(mrun, mloc);
    float al = __expf(mrun - mn);
    mrun = mn;
    float lloc = 0.f;
#pragma unroll
    for (int ms = 0; ms < 2; ++ms)
#pragma unroll
      for (int r = 0; r < 4; ++r) {
        // force e=0 on masked keys (guards all-masked-tile m=-1e30 corner too)
        float e = (kp[ms][r] != 0) ? 0.f : __expf(st[ms][r] - mrun);
        st[ms][r] = e;
        lloc += e;
      }
    lloc += __shfl_xor(lloc, 16);
    lloc += __shfl_xor(lloc, 32);
    lrun = lrun * al + lloc;
    alds[w][l15] = al;  // all quads write identical value
#pragma unroll
    for (int ms = 0; ms < 2; ++ms) {
      s16x4 pk;
#pragma unroll
      for (int r = 0; r < 4; ++r) pk[r] = f2bf(st[ms][r] * Pp.ab[ms][r]);
      *(s16x4*)&wl[w][l15 * 40 + ms * 16 + quad * 4] = pk;
    }
    f32x4 av = *(const f32x4*)&alds[w][quad * 4];
    s16x8 pf = *(const s16x8*)&wl[w][l15 * 40 + quad * 8];
#pragma unroll
    for (int ds = 0; ds < 4; ++ds) o[ds] *= av;
#pragma unroll
    for (int ds = 0; ds < 4; ++ds) {
      const int rV = ds * 16 + l15;
      s16x8 vf = *(const s16x8*)&vbuf[pb][rV * 32 + (quad ^ (rV & 3)) * 8];
      o[ds] = mfma16(pf, vf, o[ds]);
    }
  };

  // ---- prologue: group A (kpm + stage 0,1), fence, group B (packs 0,1), fence
  gload16(kpmd + w * 256 + lane * 4, &kpl[w * 256]);
  stage(0, 0);
  stage(1, 1);
  asm volatile("" ::: "memory");
  loadP(0, P[0]);
  loadP(1, P[1]);
  asm volatile("" ::: "memory");

  // ---- main loop: per iter issue {stage(t+2), loadP(t+2)} = 6 vmem ops,
  // then vmcnt(12) (retires all but the 2 youngest regions) + raw s_barrier.
#pragma unroll
  for (int t = 0; t < 32; ++t) {
    const int tn = (t + 2 < 32) ? (t + 2) : 31;  // clamp: keeps vmem count uniform
    stage(tn, (t + 2) & 3);
    loadP(tn, P[(t + 2) % 3]);
    asm volatile("s_waitcnt vmcnt(12)" ::: "memory");
    __builtin_amdgcn_s_barrier();
    asm volatile("" ::: "memory");
    compute(t, t & 3, P[t % 3]);
  }

  float rd = 1.f / (__expf(-mrun) + lrun);  // softmax_1 denominator
  alds[w][l15] = rd;
  f32x4 rdv = *(const f32x4*)&alds[w][quad * 4];
#pragma unroll
  for (int ds = 0; ds < 4; ++ds) {
    f32x4 ov = o[ds] * rdv;
#pragma unroll
    for (int r = 0; r < 4; ++r) {
      int s = qw + quad * 4 + r;
      attnbf[(size_t)(s * 4 + b_) * 1024 + h_ * 64 + ds * 16 + l15] = f2bf(ov[r]);
    }
  }
}

// ---------- launcher ----------
extern "C" void kernel_launch(void* const* d_in, const int* in_sizes, int n_in,
                              void* d_out, int out_size, void* d_ws, size_t ws_size,
                              hipStream_t stream) {
  const float* x     = (const float*)d_in[0];
  const float* bias  = (const float*)d_in[1];
  const float* abm   = (const float*)d_in[2];
  const int*   kpm   = (const int*)  d_in[3];
  const float* W_in  = (const float*)d_in[4];
  const float* b_in  = (const float*)d_in[5];
  const float* W_out = (const float*)d_in[6];
  const float* b_out = (const float*)d_in[7];
  float* out = (float*)d_out;

  char* ws = (char*)d_ws;
  short* xbf    = (short*)(ws);                              // 8 MB
  short* wibf   = (short*)(ws + (8u << 20));                 // 6 MB
  short* wobf   = (short*)(ws + (14u << 20) + (512u << 10)); // 2 MB
  short* qkvbf  = (short*)(ws + (16u << 20) + (768u << 10)); // 24 MB
  short* qh     = (short*)(ws + (40u << 20) + (768u << 10)); // 8 MB
  short* kh     = (short*)(ws + (48u << 20) + (768u << 10)); // 8 MB
  short* vTh    = (short*)(ws + (56u << 20) + (768u << 10)); // 8 MB
  short* attnbf = (short*)(ws + (64u << 20) + (768u << 10)); // 8 MB

  cast_all<<<8192, 256, 0, stream>>>(x, W_in, W_out, xbf, wibf, wobf);

  // qkv = x @ W_in^T + b_in  -> bf16
  gemm_bt<1, 4><<<dim3(24, 32), 256, 0, stream>>>(xbf, wibf, b_in, (void*)qkvbf,
                                                  4096, 3072, 1024);

  repack_all<<<dim3(64, 16), 256, 0, stream>>>(qkvbf, qh, kh, vTh);

  attn_fused<<<dim3(64, 16), 256, 0, stream>>>(qh, kh, vTh, bias, abm, kpm, attnbf);

  // out = attn @ W_out^T + b_out -> f32 (64x64 tiles: 1024 blocks = 4/CU)
  gemm_bt<0, 2><<<dim3(16, 64), 256, 0, stream>>>(attnbf, wobf, b_out, (void*)out,
                                                  4096, 1024, 1024);
}

// Round 3
// 620.461 us; speedup vs baseline: 1.1374x; 1.0594x over previous
//
#include <hip/hip_runtime.h>
#include <stdint.h>
#include <stddef.h>

// ---------- types ----------
typedef __attribute__((ext_vector_type(4))) float f32x4;
typedef __attribute__((ext_vector_type(4))) int   i32x4;
typedef __attribute__((ext_vector_type(8))) short s16x8;
typedef __attribute__((ext_vector_type(4))) short s16x4;
typedef __attribute__((ext_vector_type(8))) __bf16 bf16x8;

#define AS3 __attribute__((address_space(3)))
#define AS1 __attribute__((address_space(1)))

__device__ inline void gload16(const void* g, void* l) {
  // async global->LDS, 16B per lane; LDS dest = wave-uniform base + lane*16
  __builtin_amdgcn_global_load_lds((AS1 const void*)g, (AS3 void*)l, 16, 0, 0);
}

__device__ inline f32x4 mfma16(s16x8 a, s16x8 b, f32x4 c) {
  return __builtin_amdgcn_mfma_f32_16x16x32_bf16(
      __builtin_bit_cast(bf16x8, a), __builtin_bit_cast(bf16x8, b), c, 0, 0, 0);
}

__device__ inline short f2bf(float f) {  // RNE float->bf16 bits
  unsigned u = __builtin_bit_cast(unsigned, f);
  u += 0x7FFFu + ((u >> 16) & 1u);
  return (short)(u >> 16);
}
__device__ inline float bf2f(short x) {
  unsigned u = ((unsigned)(unsigned short)x) << 16;
  return __builtin_bit_cast(float, u);
}

// ---------- fused cast f32 -> bf16 of x, W_in, W_out (one launch) ----------
// ranges in f32x4 units: x 1048576 | W_in 786432 | W_out 262144  (total 2097152)
__global__ void cast_all(const float* __restrict__ x, const float* __restrict__ wi,
                         const float* __restrict__ wo, short* __restrict__ xb,
                         short* __restrict__ wib, short* __restrict__ wob) {
  int i = blockIdx.x * 256 + threadIdx.x;
  const float* src;
  short* dst;
  int off;
  if (i < 1048576)      { src = x;  dst = xb;  off = i; }
  else if (i < 1835008) { src = wi; dst = wib; off = i - 1048576; }
  else                  { src = wo; dst = wob; off = i - 1835008; }
  f32x4 v = *(const f32x4*)(src + (size_t)off * 4);
  s16x4 o;
#pragma unroll
  for (int r = 0; r < 4; ++r) o[r] = f2bf(v[r]);
  *(s16x4*)(dst + (size_t)off * 4) = o;
}

// ---------- GEMM: C[M][N] = A[M][K](bf16) * B[N][K](bf16)^T + bias[N] ----------
// FR=4: 128x128 tile (4 waves as 2x2 of 64x64). FR=2: 64x64 tile (2x2 of 32x32).
template <int OBF, int FR>
__global__ __launch_bounds__(256, 2) void gemm_bt(
    const short* __restrict__ A, const short* __restrict__ B,
    const float* __restrict__ bias, void* __restrict__ Cv,
    int M, int N, int K) {
  const int TILE = FR * 32;
  const int tid = threadIdx.x, w = tid >> 6, lane = tid & 63;
  const int quad = lane >> 4, l15 = lane & 15;
  const int wm = w >> 1, wn = w & 1;
  const int m0 = blockIdx.y * TILE, n0 = blockIdx.x * TILE;
  __shared__ short As[TILE * 32], Bs[TILE * 32];
  f32x4 acc[FR][FR];
#pragma unroll
  for (int i = 0; i < FR; ++i)
#pragma unroll
    for (int j = 0; j < FR; ++j) acc[i][j] = (f32x4){0.f, 0.f, 0.f, 0.f};
  const int rs = lane >> 2, cs = (lane & 3) * 8;
  const int nkt = K >> 5;
  for (int kt = 0; kt < nkt; ++kt) {
    const int k0 = kt * 32;
#pragma unroll
    for (int j = 0; j < FR / 2; ++j) {
      gload16(A + (size_t)(m0 + w * (FR * 8) + j * 16 + rs) * K + k0 + cs,
              &As[w * (FR * 256) + j * 512]);
      gload16(B + (size_t)(n0 + w * (FR * 8) + j * 16 + rs) * K + k0 + cs,
              &Bs[w * (FR * 256) + j * 512]);
    }
    __syncthreads();
    s16x8 af[FR], bfr[FR];
#pragma unroll
    for (int i = 0; i < FR; ++i) {
      af[i]  = *(const s16x8*)&As[(wm * (FR * 16) + i * 16 + l15) * 32 + quad * 8];
      bfr[i] = *(const s16x8*)&Bs[(wn * (FR * 16) + i * 16 + l15) * 32 + quad * 8];
    }
#pragma unroll
    for (int ms = 0; ms < FR; ++ms)
#pragma unroll
      for (int ns = 0; ns < FR; ++ns)
        acc[ms][ns] = mfma16(af[ms], bfr[ns], acc[ms][ns]);
    __syncthreads();
  }
#pragma unroll
  for (int ms = 0; ms < FR; ++ms) {
    const int row0 = m0 + wm * (FR * 16) + ms * 16 + quad * 4;
#pragma unroll
    for (int ns = 0; ns < FR; ++ns) {
      const int col = n0 + wn * (FR * 16) + ns * 16 + l15;
      const float bv = bias[col];
#pragma unroll
      for (int r = 0; r < 4; ++r) {
        float v = acc[ms][ns][r] + bv;
        if (OBF) ((short*)Cv)[(size_t)(row0 + r) * N + col] = f2bf(v);
        else     ((float*)Cv)[(size_t)(row0 + r) * N + col] = v;
      }
    }
  }
}

// ---------- fused repack: qkv -> qh [bh][s][d] (x1/8), kh [bh][s][d], vT [bh][d][s]
// grid (64 bh, 16 s-tiles of 64), 256 threads
__global__ void repack_all(const short* __restrict__ qkv, short* __restrict__ qh,
                           short* __restrict__ kh, short* __restrict__ vT) {
  __shared__ short t[64][80];  // v tile [s][d], pad 80 shorts (160B rows, 16B-mult)
  const int bh = blockIdx.x, st_ = blockIdx.y;
  const int b_ = bh >> 4, h_ = bh & 15;
  const int tid = threadIdx.x;
  // q/k: 64 s x 2 types x 8 chunks = 1024 chunks of 8 shorts
#pragma unroll
  for (int part = 0; part < 4; ++part) {
    int lin = part * 256 + tid;
    int dg = lin & 7, ty = (lin >> 3) & 1, s_l = lin >> 4;
    int s = st_ * 64 + s_l;
    s16x8 v = *(const s16x8*)(qkv + (size_t)(s * 4 + b_) * 3072 + h_ * 192 + ty * 64 + dg * 8);
    if (ty == 0) {
#pragma unroll
      for (int i = 0; i < 8; ++i) v[i] = f2bf(bf2f(v[i]) * 0.125f);
      *(s16x8*)&qh[((size_t)bh << 16) + (size_t)s * 64 + dg * 8] = v;
    } else {
      *(s16x8*)&kh[((size_t)bh << 16) + (size_t)s * 64 + dg * 8] = v;
    }
  }
  // v load: 64 s x 8 chunks = 512 chunks
#pragma unroll
  for (int part = 0; part < 2; ++part) {
    int lin = part * 256 + tid;
    int ch = lin & 7, s_l = lin >> 3;
    int s = st_ * 64 + s_l;
    *(s16x8*)&t[s_l][ch * 8] =
        *(const s16x8*)(qkv + (size_t)(s * 4 + b_) * 3072 + h_ * 192 + 128 + ch * 8);
  }
  __syncthreads();
  // v transpose out: 64 d x 8 s-chunks = 512 chunks
#pragma unroll
  for (int part = 0; part < 2; ++part) {
    int lin = part * 256 + tid;
    int sc = lin & 7, d_l = lin >> 3;
    s16x8 vv;
#pragma unroll
    for (int j = 0; j < 8; ++j) vv[j] = t[sc * 8 + j][d_l];
    *(s16x8*)&vT[((size_t)bh << 16) + (size_t)d_l * 1024 + st_ * 64 + sc * 8] = vv;
  }
}

// ---------- fused flash attention with softmax_1, bias add/mul, key mask ----------
// grid (64 bh, 16 q-tiles of 64), 256 thr = 4 waves, each wave 16 q; k-tiles of 32.
// Counted-vmcnt pipeline, 2-deep LDS K/V buffers, 3 rotating bias/abm packs.
// Body order: vmcnt(6) [own stage(t) landed] -> s_barrier [all waves' stage(t)
// landed AND all done compute(t-1)] -> stage(t+1) [safe: only compute(t-1) read
// buf (t+1)&1] -> loadP(t+2) -> compute(t). FIFO retirement: S gets 1-iter
// hiding (L2-resident K/V), P packs get 2-iter hiding (HBM bias/abm stream).
// No vmcnt(0) drain anywhere in the loop. LDS 25.9KB -> 4 blocks/CU (grid cap).
__global__ __launch_bounds__(256, 4) void attn_fused(
    const short* __restrict__ qh, const short* __restrict__ kh,
    const short* __restrict__ vT, const float* __restrict__ bias,
    const float* __restrict__ abm, const int* __restrict__ kpm,
    short* __restrict__ attnbf) {
  const int tid = threadIdx.x;
  const int w = tid >> 6, lane = tid & 63, quad = lane >> 4, l15 = lane & 15;
  const int bh = blockIdx.x, qb = blockIdx.y;
  const int b_ = bh >> 4, h_ = bh & 15;
  const short* qhd = qh + ((size_t)bh << 16);
  const short* khd = kh + ((size_t)bh << 16);
  const short* vTd = vT + ((size_t)bh << 16);
  const int qw = qb * 64 + w * 16;
  const float* biasd = bias + ((size_t)bh << 20) + (size_t)(qw + l15) * 1024;
  const float* abmd  = abm  + ((size_t)bh << 20) + (size_t)(qw + l15) * 1024;
  const int*   kpmd  = kpm + (b_ << 10);

  __shared__ short kbuf[2][32 * 64];   // [k][d], rows 128B, src-swizzled
  __shared__ short vbuf[2][64 * 32];   // [d][k], rows 64B, src-swizzled
  __shared__ short wl[4][16 * 40];     // per-wave P tile [q][k], pad 40
  __shared__ float alds[4][16];        // per-wave per-q broadcast
  __shared__ int   kpl[1024];          // key padding mask, staged once

  s16x8 qf[2];  // B-operand frags of Q^T (16 q rows), d-halves
#pragma unroll
  for (int t = 0; t < 2; ++t)
    qf[t] = *(const s16x8*)&qhd[(size_t)(qw + l15) * 64 + t * 32 + quad * 8];

  f32x4 o[4];
#pragma unroll
  for (int ds = 0; ds < 4; ++ds) o[ds] = (f32x4){0.f, 0.f, 0.f, 0.f};
  float mrun = -1e30f, lrun = 0.f;

  struct Pack { f32x4 bs[2]; f32x4 ab[2]; };
  Pack P[3];

  // staging with source-side XOR swizzle (LDS dest stays linear for gload16)
  const int l7 = lane & 7, lr3 = lane >> 3;         // K: row sub-idx, slot
  const int l3 = lane & 3, lr2 = (lane >> 2) & 3;   // V
  auto stage = [&](int kt, int pb) {
    // K: lane -> row rK = w*8 + (lane>>3), slot (lane&7); src slot ^= rK&7
    gload16(khd + (size_t)kt * 2048 + (size_t)(w * 8 + lr3) * 64 + (size_t)(l7 ^ lr3) * 8,
            &kbuf[pb][w * 512]);
    // V: lane -> row rV = w*16 + (lane>>2), slot (lane&3); src slot ^= rV&3
    gload16(vTd + (size_t)(w * 16 + (lane >> 2)) * 1024 + kt * 32 + (size_t)(l3 ^ lr2) * 8,
            &vbuf[pb][w * 512]);
  };
  auto loadP = [&](int kt, Pack& Pp) {
    const int kb = kt * 32;
#pragma unroll
    for (int ms = 0; ms < 2; ++ms) {
      Pp.bs[ms] = *(const f32x4*)&biasd[kb + ms * 16 + quad * 4];
      Pp.ab[ms] = *(const f32x4*)&abmd [kb + ms * 16 + quad * 4];
    }
  };

  auto compute = [&](int kt, int pb, Pack& Pp) {
    const int kb = kt * 32;
    const f32x4 z4 = {0.f, 0.f, 0.f, 0.f};
    i32x4 kp[2];
#pragma unroll
    for (int ms = 0; ms < 2; ++ms)
      kp[ms] = *(const i32x4*)&kpl[kb + ms * 16 + quad * 4];  // broadcast, free
    f32x4 st[2];  // S^T frags: rows=k (ms*16+quad*4+r), cols=q (l15)
#pragma unroll
    for (int ms = 0; ms < 2; ++ms) {
      const int rK = ms * 16 + l15;
      const int sw = rK & 7;
      s16x8 a0 = *(const s16x8*)&kbuf[pb][rK * 64 + (quad ^ sw) * 8];
      s16x8 a1 = *(const s16x8*)&kbuf[pb][rK * 64 + ((quad + 4) ^ sw) * 8];
      st[ms] = mfma16(a1, qf[1], mfma16(a0, qf[0], z4));
    }
    float mloc = -1e30f;
#pragma unroll
    for (int ms = 0; ms < 2; ++ms)
#pragma unroll
      for (int r = 0; r < 4; ++r) {
        float sc = st[ms][r] + Pp.bs[ms][r];
        sc = (kp[ms][r] != 0) ? -1e30f : sc;
        st[ms][r] = sc;
        mloc = fmaxf(mloc, sc);
      }
    mloc = fmaxf(mloc, __shfl_xor(mloc, 16));
    mloc = fmaxf(mloc, __shfl_xor(mloc, 32));
    float mn = fmaxf(mrun, mloc);
    float al = __expf(mrun - mn);
    mrun = mn;
    float lloc = 0.f;
#pragma unroll
    for (int ms = 0; ms < 2; ++ms)
#pragma unroll
      for (int r = 0; r < 4; ++r) {
        // force e=0 on masked keys (guards all-masked-tile m=-1e30 corner too)
        float e = (kp[ms][r] != 0) ? 0.f : __expf(st[ms][r] - mrun);
        st[ms][r] = e;
        lloc += e;
      }
    lloc += __shfl_xor(lloc, 16);
    lloc += __shfl_xor(lloc, 32);
    lrun = lrun * al + lloc;
    alds[w][l15] = al;  // all quads write identical value
#pragma unroll
    for (int ms = 0; ms < 2; ++ms) {
      s16x4 pk;
#pragma unroll
      for (int r = 0; r < 4; ++r) pk[r] = f2bf(st[ms][r] * Pp.ab[ms][r]);
      *(s16x4*)&wl[w][l15 * 40 + ms * 16 + quad * 4] = pk;
    }
    f32x4 av = *(const f32x4*)&alds[w][quad * 4];
    s16x8 pf = *(const s16x8*)&wl[w][l15 * 40 + quad * 8];
#pragma unroll
    for (int ds = 0; ds < 4; ++ds) o[ds] *= av;
#pragma unroll
    for (int ds = 0; ds < 4; ++ds) {
      const int rV = ds * 16 + l15;
      s16x8 vf = *(const s16x8*)&vbuf[pb][rV * 32 + (quad ^ (rV & 3)) * 8];
      o[ds] = mfma16(pf, vf, o[ds]);
    }
  };

  // ---- prologue: issue kpl + stage(0) + packs 0,1 (retired by iter-0 vmcnt(6))
  gload16(kpmd + w * 256 + lane * 4, &kpl[w * 256]);
  stage(0, 0);
  loadP(0, P[0]);
  loadP(1, P[1]);
  asm volatile("" ::: "memory");

  // ---- main loop: uniform vmcnt(6) keeps exactly the newest P-pack (6 loads)
  // in flight across the barrier; everything older (own stage(t), P(t)) retired.
#pragma unroll
  for (int t = 0; t < 32; ++t) {
    asm volatile("s_waitcnt vmcnt(6)" ::: "memory");
    __builtin_amdgcn_s_barrier();
    asm volatile("" ::: "memory");
    const int ts = (t + 1 < 32) ? (t + 1) : 31;  // clamp: uniform vmem count
    stage(ts, (t + 1) & 1);
    const int tp = (t + 2 < 32) ? (t + 2) : 31;
    loadP(tp, P[(t + 2) % 3]);
    compute(t, t & 1, P[t % 3]);
  }
  // drain clamped tail loads before LDS teardown / epilogue
  asm volatile("s_waitcnt vmcnt(0)" ::: "memory");

  float rd = 1.f / (__expf(-mrun) + lrun);  // softmax_1 denominator
  alds[w][l15] = rd;
  f32x4 rdv = *(const f32x4*)&alds[w][quad * 4];
#pragma unroll
  for (int ds = 0; ds < 4; ++ds) {
    f32x4 ov = o[ds] * rdv;
#pragma unroll
    for (int r = 0; r < 4; ++r) {
      int s = qw + quad * 4 + r;
      attnbf[(size_t)(s * 4 + b_) * 1024 + h_ * 64 + ds * 16 + l15] = f2bf(ov[r]);
    }
  }
}

// ---------- launcher ----------
extern "C" void kernel_launch(void* const* d_in, const int* in_sizes, int n_in,
                              void* d_out, int out_size, void* d_ws, size_t ws_size,
                              hipStream_t stream) {
  const float* x     = (const float*)d_in[0];
  const float* bias  = (const float*)d_in[1];
  const float* abm   = (const float*)d_in[2];
  const int*   kpm   = (const int*)  d_in[3];
  const float* W_in  = (const float*)d_in[4];
  const float* b_in  = (const float*)d_in[5];
  const float* W_out = (const float*)d_in[6];
  const float* b_out = (const float*)d_in[7];
  float* out = (float*)d_out;

  char* ws = (char*)d_ws;
  short* xbf    = (short*)(ws);                              // 8 MB
  short* wibf   = (short*)(ws + (8u << 20));                 // 6 MB
  short* wobf   = (short*)(ws + (14u << 20) + (512u << 10)); // 2 MB
  short* qkvbf  = (short*)(ws + (16u << 20) + (768u << 10)); // 24 MB
  short* qh     = (short*)(ws + (40u << 20) + (768u << 10)); // 8 MB
  short* kh     = (short*)(ws + (48u << 20) + (768u << 10)); // 8 MB
  short* vTh    = (short*)(ws + (56u << 20) + (768u << 10)); // 8 MB
  short* attnbf = (short*)(ws + (64u << 20) + (768u << 10)); // 8 MB

  cast_all<<<8192, 256, 0, stream>>>(x, W_in, W_out, xbf, wibf, wobf);

  // qkv = x @ W_in^T + b_in  -> bf16
  gemm_bt<1, 4><<<dim3(24, 32), 256, 0, stream>>>(xbf, wibf, b_in, (void*)qkvbf,
                                                  4096, 3072, 1024);

  repack_all<<<dim3(64, 16), 256, 0, stream>>>(qkvbf, qh, kh, vTh);

  attn_fused<<<dim3(64, 16), 256, 0, stream>>>(qh, kh, vTh, bias, abm, kpm, attnbf);

  // out = attn @ W_out^T + b_out -> f32 (64x64 tiles: 1024 blocks = 4/CU)
  gemm_bt<0, 2><<<dim3(16, 64), 256, 0, stream>>>(attnbf, wobf, b_out, (void*)out,
                                                  4096, 1024, 1024);
}